// Round 1
// baseline (499.320 us; speedup 1.0000x reference)
//
#include <hip/hip_runtime.h>
#include <hip/hip_bf16.h>
#include <cstddef>

#define BB 16
#define TT 4096
#define HH 512

typedef _Float16 half8 __attribute__((ext_vector_type(8)));
typedef _Float16 half4 __attribute__((ext_vector_type(4)));
typedef float f32x4 __attribute__((ext_vector_type(4)));

// ---------------- prep: Wv->f16, qb = q@Wq^T + bias + conv_b, zero ssum/ctx ----
__global__ void prep_kernel(const float* __restrict__ query,
                            const float* __restrict__ conv_b,
                            const float* __restrict__ Wq,
                            const float* __restrict__ Wv,
                            const float* __restrict__ bias,
                            _Float16* __restrict__ Wh,
                            float* __restrict__ qb,
                            float* __restrict__ ssum,
                            float* __restrict__ ctx) {
    int blk = blockIdx.x;
    int tid = threadIdx.x;
    if (blk < 32) {
        int base = blk * 8192;
        for (int i = tid; i < 8192; i += 256)
            Wh[base + i] = (_Float16)Wv[base + i];
    } else if (blk < 48) {
        int b = blk - 32;
        __shared__ float qrow[HH];
        for (int i = tid; i < HH; i += 256) qrow[i] = query[b * HH + i];
        __syncthreads();
        for (int o = tid; o < HH; o += 256) {
            const float* w = Wq + (size_t)o * HH;
            float acc = 0.f;
            #pragma unroll 4
            for (int h = 0; h < HH; ++h) acc += qrow[h] * w[h];
            qb[b * HH + o] = acc + bias[o] + conv_b[o];
        }
    } else {
        for (int i = tid; i < BB; i += 256) ssum[i] = 0.f;
        for (int i = tid; i < BB * HH; i += 256) ctx[i] = 0.f;
    }
}

// ---------------- main fused GEMM + conv + tanh + score ------------------------
// grid: 1024 blocks (64 per b), block: 1024 threads = 16 waves
// block computes 64 rows (t) x 512 cols (o), K=512
// wave w: msub = w&3 (16 rows), nq = w>>2 (128 cols = 8 mfma tiles)
__global__ __launch_bounds__(1024) void gemm_score_kernel(
        const float* __restrict__ value,
        const float* __restrict__ last_attn,
        const float* __restrict__ conv_w,
        const float* __restrict__ w_score,
        const float* __restrict__ b_score,
        const _Float16* __restrict__ Wh,
        const float* __restrict__ qb,
        float* __restrict__ sbuf,
        float* __restrict__ ssum) {
    __shared__ _Float16 As[64 * 264];      // 64 rows x 256 k (+8 pad), per phase
    __shared__ float cw0[HH], cw1[HH], cw2[HH], wsc[HH], qbs[HH];
    __shared__ float las[66];
    __shared__ float sred[64][4];

    int tid = threadIdx.x;
    int bm  = blockIdx.x;
    int b   = bm >> 6;
    int t0  = (bm & 63) << 6;

    const float* src = value + ((size_t)(b * TT + t0)) * HH;

    if (tid < 512) {
        int o = tid;
        cw0[o] = conv_w[o * 3 + 0];
        cw1[o] = conv_w[o * 3 + 1];
        cw2[o] = conv_w[o * 3 + 2];
        wsc[o] = w_score[o];
        qbs[o] = qb[b * HH + o];
    } else if (tid < 512 + 66) {
        int i = tid - 512;
        int t = t0 - 1 + i;
        las[i] = (t >= 0 && t < TT) ? last_attn[b * TT + t] : 0.f;
    }

    int wave = tid >> 6, lane = tid & 63;
    int msub = wave & 3, nq = wave >> 2;
    int quad = lane >> 4, lm = lane & 15;
    int r = msub * 16 + lm;

    f32x4 acc[8];
    #pragma unroll
    for (int i = 0; i < 8; ++i) { f32x4 z = {0.f, 0.f, 0.f, 0.f}; acc[i] = z; }

    const _Float16* Ab = &As[r * 264 + quad * 8];
    const _Float16* Bb = Wh + (size_t)(nq * 128 + lm) * HH + quad * 8;

    for (int kp = 0; kp < 2; ++kp) {
        __syncthreads();   // previous phase fully consumed (also covers weight staging)
        // stage 64 rows x 256 floats -> f16 LDS
        #pragma unroll
        for (int i = 0; i < 4; ++i) {
            int idx = tid + i * 1024;          // 4096 float4
            int row = idx >> 6, c4 = idx & 63;
            float4 v4 = ((const float4*)(src + (size_t)row * HH + kp * 256))[c4];
            half4 h4 = { (_Float16)v4.x, (_Float16)v4.y, (_Float16)v4.z, (_Float16)v4.w };
            *(half4*)(&As[row * 264 + c4 * 4]) = h4;
        }
        __syncthreads();
        #pragma unroll
        for (int k0 = 0; k0 < 256; k0 += 32) {
            half8 a = *(const half8*)(Ab + k0);
            #pragma unroll
            for (int nt = 0; nt < 8; ++nt) {
                half8 bf = *(const half8*)(Bb + (size_t)nt * 16 * HH + kp * 256 + k0);
                acc[nt] = __builtin_amdgcn_mfma_f32_16x16x32_f16(a, bf, acc[nt], 0, 0, 0);
            }
        }
    }

    // epilogue: act = v + qb + conv;  e = tanh(act);  rowsum += e * w_score
    float rs[4] = {0.f, 0.f, 0.f, 0.f};
    #pragma unroll
    for (int nt = 0; nt < 8; ++nt) {
        int o = nq * 128 + nt * 16 + lm;
        float c0 = cw0[o], c1 = cw1[o], c2 = cw2[o], qv = qbs[o], wv = wsc[o];
        #pragma unroll
        for (int j = 0; j < 4; ++j) {
            int m = msub * 16 + quad * 4 + j;
            float act = acc[nt][j] + qv + c0 * las[m] + c1 * las[m + 1] + c2 * las[m + 2];
            act = fminf(15.f, fmaxf(-15.f, act));
            float e2 = __expf(2.f * act);
            float th = (e2 - 1.f) / (e2 + 1.f);
            rs[j] += th * wv;
        }
    }
    // reduce across the 16 column-lanes (same quad)
    #pragma unroll
    for (int j = 0; j < 4; ++j)
        for (int off = 1; off < 16; off <<= 1)
            rs[j] += __shfl_xor(rs[j], off, 64);
    if (lm == 0) {
        #pragma unroll
        for (int j = 0; j < 4; ++j)
            sred[msub * 16 + quad * 4 + j][nq] = rs[j];
    }
    __syncthreads();
    if (tid < 64) {
        int m = tid;
        float sc = sred[m][0] + sred[m][1] + sred[m][2] + sred[m][3] + b_score[0];
        float s = 1.f / (1.f + __expf(-sc));
        sbuf[b * TT + t0 + m] = s;
        float tot = s;
        for (int off = 1; off < 64; off <<= 1) tot += __shfl_xor(tot, off, 64);
        if (tid == 0) atomicAdd(&ssum[b], tot);
    }
}

// ---------------- context partials: ctx[b][h] += sum_t s[b,t]*value[b,t,h] -----
// grid 1024: b(16) x hq(2) x tq(32); block 256 threads
__global__ void context_kernel(const float* __restrict__ value,
                               const float* __restrict__ sbuf,
                               float* __restrict__ ctx) {
    int blk = blockIdx.x;
    int b = blk >> 6;
    int rem = blk & 63;
    int hq = rem >> 5;
    int tq = rem & 31;
    int tid = threadIdx.x;
    int h = hq * 256 + tid;
    const float* vp = value + ((size_t)b * TT + (size_t)tq * 128) * HH + h;
    const float* sp = sbuf + b * TT + tq * 128;
    float a0 = 0.f, a1 = 0.f, a2 = 0.f, a3 = 0.f;
    #pragma unroll 4
    for (int t = 0; t < 128; t += 4) {
        a0 += sp[t + 0] * vp[(size_t)(t + 0) * HH];
        a1 += sp[t + 1] * vp[(size_t)(t + 1) * HH];
        a2 += sp[t + 2] * vp[(size_t)(t + 2) * HH];
        a3 += sp[t + 3] * vp[(size_t)(t + 3) * HH];
    }
    atomicAdd(&ctx[b * HH + h], (a0 + a1) + (a2 + a3));
}

// ---------------- finalize: out = [ctx/ssum, query] ++ attn = s/ssum -----------
__global__ void finalize_kernel(const float* __restrict__ query,
                                const float* __restrict__ ctx,
                                const float* __restrict__ sbuf,
                                const float* __restrict__ ssum,
                                float* __restrict__ out) {
    int idx = blockIdx.x * 256 + threadIdx.x;
    if (idx < BB * 2 * HH) {
        int b = idx >> 10, c = idx & 1023;
        float v;
        if (c < HH) v = ctx[b * HH + c] / ssum[b];
        else        v = query[b * HH + (c - HH)];
        out[idx] = v;
    } else {
        int j = idx - BB * 2 * HH;
        int b = j >> 12, t = j & 4095;
        out[idx] = sbuf[b * TT + t] / ssum[b];
    }
}

extern "C" void kernel_launch(void* const* d_in, const int* in_sizes, int n_in,
                              void* d_out, int out_size, void* d_ws, size_t ws_size,
                              hipStream_t stream) {
    const float* query     = (const float*)d_in[0];
    const float* value     = (const float*)d_in[1];
    const float* last_attn = (const float*)d_in[2];
    const float* conv_w    = (const float*)d_in[3];
    const float* conv_b    = (const float*)d_in[4];
    const float* Wq        = (const float*)d_in[5];
    const float* Wv        = (const float*)d_in[6];
    const float* bias      = (const float*)d_in[7];
    const float* w_score   = (const float*)d_in[8];
    const float* b_score   = (const float*)d_in[9];

    char* ws = (char*)d_ws;
    _Float16* Wh  = (_Float16*)ws;             // 524288 B
    float* qb     = (float*)(ws + 524288);     // 32768 B
    float* sbuf   = (float*)(ws + 557056);     // 262144 B
    float* ssum   = (float*)(ws + 819200);     // 64 B
    float* ctx    = (float*)(ws + 819264);     // 32768 B
    float* out    = (float*)d_out;

    prep_kernel<<<49, 256, 0, stream>>>(query, conv_b, Wq, Wv, bias, Wh, qb, ssum, ctx);
    gemm_score_kernel<<<1024, 1024, 0, stream>>>(value, last_attn, conv_w, w_score,
                                                 b_score, Wh, qb, sbuf, ssum);
    context_kernel<<<1024, 256, 0, stream>>>(value, sbuf, ctx);
    finalize_kernel<<<320, 256, 0, stream>>>(query, ctx, sbuf, ssum, out);
}

// Round 2
// 435.875 us; speedup vs baseline: 1.1456x; 1.1456x over previous
//
#include <hip/hip_runtime.h>
#include <hip/hip_bf16.h>
#include <cstddef>

#define BB 16
#define TT 4096
#define HH 512

typedef _Float16 half8 __attribute__((ext_vector_type(8)));
typedef _Float16 half4 __attribute__((ext_vector_type(4)));
typedef float f32x4 __attribute__((ext_vector_type(4)));

// ---------------- prep ---------------------------------------------------------
// blocks 0..31 : pack Wv (f32, [n][k]) -> Bpack f16 in MFMA B-fragment order:
//                Bpack[TN(32)][kb(16)][lane(64)][j(8)], TN=n>>4, kb=k>>5,
//                lane=((k>>3)&3)*16 + (n&15), j=k&7
// blocks 32..47: qb[b][o] = query[b]·Wq[o] + bias[o] + conv_b[o]  (wave-coop dot)
// block  48    : zero ssum/ctx
__global__ void prep_kernel(const float* __restrict__ query,
                            const float* __restrict__ conv_b,
                            const float* __restrict__ Wq,
                            const float* __restrict__ Wv,
                            const float* __restrict__ bias,
                            _Float16* __restrict__ Bpack,
                            float* __restrict__ qb,
                            float* __restrict__ ssum,
                            float* __restrict__ ctx) {
    int blk = blockIdx.x;
    int tid = threadIdx.x;
    if (blk < 32) {
        int base = blk * 8192;
        for (int i = 0; i < 32; ++i) {
            int idx = base + tid + i * 256;
            int n = idx >> 9, k = idx & 511;
            int lane = ((k >> 3) & 3) * 16 + (n & 15);
            int off = (n >> 4) * 8192 + (k >> 5) * 512 + lane * 8 + (k & 7);
            Bpack[off] = (_Float16)Wv[idx];
        }
    } else if (blk < 48) {
        int b = blk - 32;
        __shared__ float qrow[HH];
        for (int i = tid; i < HH; i += 256) qrow[i] = query[b * HH + i];
        __syncthreads();
        int wave = tid >> 6, lane = tid & 63;
        float4 q1 = *(const float4*)(qrow + lane * 8);
        float4 q2 = *(const float4*)(qrow + lane * 8 + 4);
        for (int o = wave; o < HH; o += 4) {
            const float4* w = (const float4*)(Wq + (size_t)o * HH);
            float4 a = w[lane * 2], c = w[lane * 2 + 1];
            float acc = a.x * q1.x + a.y * q1.y + a.z * q1.z + a.w * q1.w
                      + c.x * q2.x + c.y * q2.y + c.z * q2.z + c.w * q2.w;
            #pragma unroll
            for (int off = 1; off < 64; off <<= 1) acc += __shfl_xor(acc, off, 64);
            if (lane == 0) qb[b * HH + o] = acc + bias[o] + conv_b[o];
        }
    } else {
        for (int i = tid; i < BB; i += 256) ssum[i] = 0.f;
        for (int i = tid; i < BB * HH; i += 256) ctx[i] = 0.f;
    }
}

// ---------------- main fused GEMM + conv + tanh + score ------------------------
// grid: 1024 blocks (64 per b), block: 1024 threads = 16 waves
// block computes 64 rows (t) x 512 cols (o), K=512
// wave w: msub = w&3 (16 rows), nq = w>>2 (128 cols = 8 mfma tiles)
__global__ __launch_bounds__(1024) void gemm_score_kernel(
        const float* __restrict__ value,
        const float* __restrict__ last_attn,
        const float* __restrict__ conv_w,
        const float* __restrict__ w_score,
        const float* __restrict__ b_score,
        const _Float16* __restrict__ Bpack,
        const float* __restrict__ qb,
        float* __restrict__ sbuf,
        float* __restrict__ ssum) {
    __shared__ _Float16 As[64 * 264];      // 64 rows x 256 k (+8 pad), per phase
    __shared__ float cw0[HH], cw1[HH], cw2[HH], wsc[HH], qbs[HH];
    __shared__ float las[66];
    __shared__ float sred[64][4];

    int tid = threadIdx.x;
    int bm  = blockIdx.x;
    int b   = bm >> 6;
    int t0  = (bm & 63) << 6;

    const float* src = value + ((size_t)(b * TT + t0)) * HH;

    if (tid < 512) {
        int o = tid;
        cw0[o] = conv_w[o * 3 + 0];
        cw1[o] = conv_w[o * 3 + 1];
        cw2[o] = conv_w[o * 3 + 2];
        wsc[o] = w_score[o];
        qbs[o] = qb[b * HH + o];
    } else if (tid < 512 + 66) {
        int i = tid - 512;
        int t = t0 - 1 + i;
        las[i] = (t >= 0 && t < TT) ? last_attn[b * TT + t] : 0.f;
    }

    int wave = tid >> 6, lane = tid & 63;
    int msub = wave & 3, nq = wave >> 2;
    int quad = lane >> 4, lm = lane & 15;
    int r = msub * 16 + lm;

    f32x4 acc[8];
    #pragma unroll
    for (int i = 0; i < 8; ++i) { f32x4 z = {0.f, 0.f, 0.f, 0.f}; acc[i] = z; }

    const _Float16* Ab = &As[r * 264 + quad * 8];
    // B fragments: contiguous 1 KiB per wave-load, L1-resident
    const _Float16* Bq = Bpack + (size_t)nq * 8 * 8192 + lane * 8;

    for (int kp = 0; kp < 2; ++kp) {
        __syncthreads();   // previous phase fully consumed (also covers weight staging)
        // stage 64 rows x 256 floats -> f16 LDS
        #pragma unroll
        for (int i = 0; i < 4; ++i) {
            int idx = tid + i * 1024;          // 4096 float4
            int row = idx >> 6, c4 = idx & 63;
            float4 v4 = ((const float4*)(src + (size_t)row * HH + kp * 256))[c4];
            half4 h4 = { (_Float16)v4.x, (_Float16)v4.y, (_Float16)v4.z, (_Float16)v4.w };
            *(half4*)(&As[row * 264 + c4 * 4]) = h4;
        }
        __syncthreads();
        #pragma unroll
        for (int k0 = 0; k0 < 256; k0 += 32) {
            half8 a = *(const half8*)(Ab + k0);
            int kb = kp * 8 + (k0 >> 5);
            #pragma unroll
            for (int nt = 0; nt < 8; ++nt) {
                half8 bf = *(const half8*)(Bq + nt * 8192 + kb * 512);
                acc[nt] = __builtin_amdgcn_mfma_f32_16x16x32_f16(a, bf, acc[nt], 0, 0, 0);
            }
        }
    }

    // epilogue: act = v + qb + conv;  e = tanh(act);  rowsum += e * w_score
    float rs[4] = {0.f, 0.f, 0.f, 0.f};
    #pragma unroll
    for (int nt = 0; nt < 8; ++nt) {
        int o = nq * 128 + nt * 16 + lm;
        float c0 = cw0[o], c1 = cw1[o], c2 = cw2[o], qv = qbs[o], wv = wsc[o];
        #pragma unroll
        for (int j = 0; j < 4; ++j) {
            int m = msub * 16 + quad * 4 + j;
            float act = acc[nt][j] + qv + c0 * las[m] + c1 * las[m + 1] + c2 * las[m + 2];
            act = fminf(15.f, fmaxf(-15.f, act));
            float e2 = __expf(2.f * act);
            float th = (e2 - 1.f) / (e2 + 1.f);
            rs[j] += th * wv;
        }
    }
    // reduce across the 16 column-lanes (same quad)
    #pragma unroll
    for (int j = 0; j < 4; ++j)
        for (int off = 1; off < 16; off <<= 1)
            rs[j] += __shfl_xor(rs[j], off, 64);
    if (lm == 0) {
        #pragma unroll
        for (int j = 0; j < 4; ++j)
            sred[msub * 16 + quad * 4 + j][nq] = rs[j];
    }
    __syncthreads();
    if (tid < 64) {
        int m = tid;
        float sc = sred[m][0] + sred[m][1] + sred[m][2] + sred[m][3] + b_score[0];
        float s = 1.f / (1.f + __expf(-sc));
        sbuf[b * TT + t0 + m] = s;
        float tot = s;
        for (int off = 1; off < 64; off <<= 1) tot += __shfl_xor(tot, off, 64);
        if (tid == 0) atomicAdd(&ssum[b], tot);
    }
}

// ---------------- context partials: ctx[b][h] += sum_t s[b,t]*value[b,t,h] -----
// grid 1024: b(16) x tq(64, 64 t each); block 256: tg=tid>>7 (2 t-halves),
// hv=tid&127 (float4 column). Coalesced 1 KiB per wave-load.
__global__ void context_kernel(const float* __restrict__ value,
                               const float* __restrict__ sbuf,
                               float* __restrict__ ctx) {
    __shared__ float4 red[128];
    int blk = blockIdx.x;
    int b = blk >> 6;
    int tq = blk & 63;
    int tid = threadIdx.x;
    int tg = tid >> 7, hv = tid & 127;
    int tbase = tq * 64 + tg * 32;
    const float4* vp = (const float4*)(value + ((size_t)b * TT + tbase) * HH) + hv;
    const float* sp = sbuf + b * TT + tbase;
    float4 acc = {0.f, 0.f, 0.f, 0.f};
    #pragma unroll 4
    for (int t = 0; t < 32; ++t) {
        float s = sp[t];
        float4 v = vp[(size_t)t * 128];
        acc.x += s * v.x; acc.y += s * v.y; acc.z += s * v.z; acc.w += s * v.w;
    }
    if (tg == 1) red[hv] = acc;
    __syncthreads();
    if (tg == 0) {
        float4 o = red[hv];
        acc.x += o.x; acc.y += o.y; acc.z += o.z; acc.w += o.w;
        float* c = ctx + b * HH + hv * 4;
        atomicAdd(c + 0, acc.x);
        atomicAdd(c + 1, acc.y);
        atomicAdd(c + 2, acc.z);
        atomicAdd(c + 3, acc.w);
    }
}

// ---------------- finalize: out = [ctx/ssum, query] ++ attn = s/ssum -----------
__global__ void finalize_kernel(const float* __restrict__ query,
                                const float* __restrict__ ctx,
                                const float* __restrict__ sbuf,
                                const float* __restrict__ ssum,
                                float* __restrict__ out) {
    int idx = blockIdx.x * 256 + threadIdx.x;
    if (idx < BB * 2 * HH) {
        int b = idx >> 10, c = idx & 1023;
        float v;
        if (c < HH) v = ctx[b * HH + c] / ssum[b];
        else        v = query[b * HH + (c - HH)];
        out[idx] = v;
    } else {
        int j = idx - BB * 2 * HH;
        int b = j >> 12, t = j & 4095;
        out[idx] = sbuf[b * TT + t] / ssum[b];
    }
}

extern "C" void kernel_launch(void* const* d_in, const int* in_sizes, int n_in,
                              void* d_out, int out_size, void* d_ws, size_t ws_size,
                              hipStream_t stream) {
    const float* query     = (const float*)d_in[0];
    const float* value     = (const float*)d_in[1];
    const float* last_attn = (const float*)d_in[2];
    const float* conv_w    = (const float*)d_in[3];
    const float* conv_b    = (const float*)d_in[4];
    const float* Wq        = (const float*)d_in[5];
    const float* Wv        = (const float*)d_in[6];
    const float* bias      = (const float*)d_in[7];
    const float* w_score   = (const float*)d_in[8];
    const float* b_score   = (const float*)d_in[9];

    char* ws = (char*)d_ws;
    _Float16* Bpack = (_Float16*)ws;           // 524288 B
    float* qb     = (float*)(ws + 524288);     // 32768 B
    float* sbuf   = (float*)(ws + 557056);     // 262144 B
    float* ssum   = (float*)(ws + 819200);     // 64 B
    float* ctx    = (float*)(ws + 819264);     // 32768 B
    float* out    = (float*)d_out;

    prep_kernel<<<49, 256, 0, stream>>>(query, conv_b, Wq, Wv, bias, Bpack, qb, ssum, ctx);
    gemm_score_kernel<<<1024, 1024, 0, stream>>>(value, last_attn, conv_w, w_score,
                                                 b_score, Bpack, qb, sbuf, ssum);
    context_kernel<<<1024, 256, 0, stream>>>(value, sbuf, ctx);
    finalize_kernel<<<320, 256, 0, stream>>>(query, ctx, sbuf, ssum, out);
}

// Round 3
// 295.757 us; speedup vs baseline: 1.6883x; 1.4738x over previous
//
#include <hip/hip_runtime.h>
#include <hip/hip_bf16.h>
#include <cstddef>

#define BB 16
#define TT 4096
#define HH 512

typedef _Float16 half8 __attribute__((ext_vector_type(8)));
typedef float f32x4 __attribute__((ext_vector_type(4)));

// ---------------- prep ---------------------------------------------------------
// blocks 0..31 : pack Wv (f32, [n][k]) -> Bpack f16 in MFMA B-fragment order:
//                Bpack[TN(32)][kb(16)][lane(64)][j(8)], TN=n>>4, kb=k>>5,
//                lane=((k>>3)&3)*16 + (n&15), j=k&7
// blocks 32..95: qb[b][o] = query[b]·Wq[o] + bias[o] + conv_b[o]  (4 blocks / b)
// block  96    : zero ssum/ctx
__global__ void prep_kernel(const float* __restrict__ query,
                            const float* __restrict__ conv_b,
                            const float* __restrict__ Wq,
                            const float* __restrict__ Wv,
                            const float* __restrict__ bias,
                            _Float16* __restrict__ Bpack,
                            float* __restrict__ qb,
                            float* __restrict__ ssum,
                            float* __restrict__ ctx) {
    int blk = blockIdx.x;
    int tid = threadIdx.x;
    if (blk < 32) {
        int base = blk * 8192;
        for (int i = 0; i < 32; ++i) {
            int idx = base + tid + i * 256;
            int n = idx >> 9, k = idx & 511;
            int lane = ((k >> 3) & 3) * 16 + (n & 15);
            int off = (n >> 4) * 8192 + (k >> 5) * 512 + lane * 8 + (k & 7);
            Bpack[off] = (_Float16)Wv[idx];
        }
    } else if (blk < 96) {
        int q = blk - 32;
        int b = q >> 2, oq = q & 3;
        __shared__ float qrow[HH];
        for (int i = tid; i < HH; i += 256) qrow[i] = query[b * HH + i];
        __syncthreads();
        int wave = tid >> 6, lane = tid & 63;
        float4 q1 = *(const float4*)(qrow + lane * 8);
        float4 q2 = *(const float4*)(qrow + lane * 8 + 4);
        for (int i = wave; i < 128; i += 4) {
            int o = oq * 128 + i;
            const float4* w = (const float4*)(Wq + (size_t)o * HH);
            float4 a = w[lane * 2], c = w[lane * 2 + 1];
            float acc = a.x * q1.x + a.y * q1.y + a.z * q1.z + a.w * q1.w
                      + c.x * q2.x + c.y * q2.y + c.z * q2.z + c.w * q2.w;
            #pragma unroll
            for (int off = 1; off < 64; off <<= 1) acc += __shfl_xor(acc, off, 64);
            if (lane == 0) qb[b * HH + o] = acc + bias[o] + conv_b[o];
        }
    } else {
        for (int i = tid; i < BB; i += 256) ssum[i] = 0.f;
        for (int i = tid; i < BB * HH; i += 256) ctx[i] = 0.f;
    }
}

// ---------------- fused GEMM + conv + tanh + score + sigmoid + context ---------
// grid 1024 = 16 b x 64 t-tiles; block 512 thr = 8 waves.
// Block tile: 64 t x 512 o, K=512 in 16 phases of k32.
// Wave ng (0..7) owns o in [ng*64, ng*64+64): 4x4 mfma tiles of 16x16.
// As: full 64x512 f16 value tile, xor-chunk-swizzled; doubles as data for the
// context reduction at the end (value is read from HBM exactly once).
__global__ __launch_bounds__(512, 4) void gemm_fused_kernel(
        const float* __restrict__ value,
        const float* __restrict__ last_attn,
        const float* __restrict__ conv_w,
        const float* __restrict__ w_score,
        const float* __restrict__ b_score,
        const _Float16* __restrict__ Bpack,
        const float* __restrict__ qb,
        float* __restrict__ sbuf,
        float* __restrict__ ssum,
        float* __restrict__ ctx) {
    __shared__ _Float16 As[64 * 512];   // 64 KiB
    __shared__ float sred[64][8];
    __shared__ float s_lds[64];

    int tid = threadIdx.x;
    int blk = blockIdx.x;
    int b = blk >> 6;
    int t0 = (blk & 63) << 6;

    int lane = tid & 63, ng = tid >> 6;
    int quad = lane >> 4, lm = lane & 15;
    int t = tid >> 3, g = tid & 7;      // staging coords: row t (0..63), 16-k group g

    const float* pA = value + ((size_t)(b * TT + t0 + t)) * HH + g * 16;

    f32x4 acc[4][4];
    #pragma unroll
    for (int mt = 0; mt < 4; ++mt)
        #pragma unroll
        for (int nt = 0; nt < 4; ++nt) { f32x4 z = {0.f,0.f,0.f,0.f}; acc[mt][nt] = z; }

    float4 ar[4];
    half8 breg[2][4];

    auto loadA = [&](int ck) {
        const float4* p = (const float4*)(pA + ck * 128);
        #pragma unroll
        for (int i = 0; i < 4; ++i) ar[i] = p[i];
    };
    auto writeA = [&](int ck) {
        #pragma unroll
        for (int u = 0; u < 2; ++u) {
            int c_log = ck * 16 + g * 2 + u;
            int cph = c_log ^ (t & 7);
            float4 v0 = ar[2 * u], v1 = ar[2 * u + 1];
            half8 h = { (_Float16)v0.x, (_Float16)v0.y, (_Float16)v0.z, (_Float16)v0.w,
                        (_Float16)v1.x, (_Float16)v1.y, (_Float16)v1.z, (_Float16)v1.w };
            *(half8*)(As + t * 512 + cph * 8) = h;
        }
    };
    auto loadB = [&](half8* dst, int p) {
        #pragma unroll
        for (int nt = 0; nt < 4; ++nt)
            dst[nt] = *(const half8*)(Bpack + (size_t)((ng * 4 + nt) * 16 + p) * 512 + lane * 8);
    };
    auto compute = [&](int p, const half8* bb) {
        #pragma unroll
        for (int mt = 0; mt < 4; ++mt) {
            int tr = mt * 16 + lm;
            int cph = (p * 4 + quad) ^ (tr & 7);
            half8 a = *(const half8*)(As + tr * 512 + cph * 8);
            #pragma unroll
            for (int nt = 0; nt < 4; ++nt)
                acc[mt][nt] = __builtin_amdgcn_mfma_f32_16x16x32_f16(a, bb[nt], acc[mt][nt], 0, 0, 0);
        }
    };

    // prologue
    loadA(0);
    loadB(breg[0], 0);
    writeA(0);
    loadA(1);
    __syncthreads();

    #pragma unroll
    for (int ck = 0; ck < 4; ++ck) {
        #pragma unroll
        for (int pp = 0; pp < 4; ++pp) {
            int p = ck * 4 + pp;
            if (p < 15) loadB(breg[(p + 1) & 1], p + 1);
            compute(p, breg[p & 1]);
        }
        if (ck < 3) {
            writeA(ck + 1);
            if (ck < 2) loadA(ck + 2);
            __syncthreads();
        }
    }

    // ---------- epilogue: conv + tanh + w_score dot ----------
    float qvv[4], c0v[4], c1v[4], c2v[4], wvv[4];
    #pragma unroll
    for (int nt = 0; nt < 4; ++nt) {
        int o = ng * 64 + nt * 16 + lm;
        qvv[nt] = qb[b * HH + o];
        c0v[nt] = conv_w[o * 3 + 0];
        c1v[nt] = conv_w[o * 3 + 1];
        c2v[nt] = conv_w[o * 3 + 2];
        wvv[nt] = w_score[o];
    }
    float rs[4][4];
    #pragma unroll
    for (int mt = 0; mt < 4; ++mt) {
        #pragma unroll
        for (int j = 0; j < 4; ++j) {
            int tg = t0 + mt * 16 + quad * 4 + j;
            const float* la = last_attn + b * TT + tg;
            float lam = (tg > 0) ? la[-1] : 0.f;
            float la0 = la[0];
            float lap = (tg < TT - 1) ? la[1] : 0.f;
            float r = 0.f;
            #pragma unroll
            for (int nt = 0; nt < 4; ++nt) {
                float act = acc[mt][nt][j] + qvv[nt]
                          + c0v[nt] * lam + c1v[nt] * la0 + c2v[nt] * lap;
                act = fminf(15.f, fmaxf(-15.f, act));
                float e2 = __expf(2.f * act);
                r += ((e2 - 1.f) / (e2 + 1.f)) * wvv[nt];
            }
            rs[mt][j] = r;
        }
    }
    #pragma unroll
    for (int mt = 0; mt < 4; ++mt)
        #pragma unroll
        for (int j = 0; j < 4; ++j) {
            #pragma unroll
            for (int off = 1; off < 16; off <<= 1)
                rs[mt][j] += __shfl_xor(rs[mt][j], off, 64);
            if (lm == 0) sred[mt * 16 + quad * 4 + j][ng] = rs[mt][j];
        }
    __syncthreads();

    if (tid < 64) {
        float sc = b_score[0];
        #pragma unroll
        for (int k = 0; k < 8; ++k) sc += sred[tid][k];
        float s = 1.f / (1.f + __expf(-sc));
        s_lds[tid] = s;
        sbuf[b * TT + t0 + tid] = s;
        float tot = s;
        #pragma unroll
        for (int off = 1; off < 64; off <<= 1) tot += __shfl_xor(tot, off, 64);
        if (tid == 0) atomicAdd(&ssum[b], tot);
    }
    __syncthreads();

    // ---------- context partial from the resident f16 tile ----------
    int h = tid;
    int jh = h & 7, clh = h >> 3;
    float a = 0.f;
    #pragma unroll 8
    for (int t2 = 0; t2 < 64; ++t2) {
        int cph = clh ^ (t2 & 7);
        a += s_lds[t2] * (float)As[t2 * 512 + cph * 8 + jh];
    }
    atomicAdd(&ctx[b * HH + h], a);
}

// ---------------- finalize: out = [ctx/ssum, query] ++ attn = s/ssum -----------
__global__ void finalize_kernel(const float* __restrict__ query,
                                const float* __restrict__ ctx,
                                const float* __restrict__ sbuf,
                                const float* __restrict__ ssum,
                                float* __restrict__ out) {
    int idx = blockIdx.x * 256 + threadIdx.x;
    if (idx < BB * 2 * HH) {
        int b = idx >> 10, c = idx & 1023;
        float v;
        if (c < HH) v = ctx[b * HH + c] / ssum[b];
        else        v = query[b * HH + (c - HH)];
        out[idx] = v;
    } else {
        int j = idx - BB * 2 * HH;
        int b = j >> 12, t = j & 4095;
        out[idx] = sbuf[b * TT + t] / ssum[b];
    }
}

extern "C" void kernel_launch(void* const* d_in, const int* in_sizes, int n_in,
                              void* d_out, int out_size, void* d_ws, size_t ws_size,
                              hipStream_t stream) {
    const float* query     = (const float*)d_in[0];
    const float* value     = (const float*)d_in[1];
    const float* last_attn = (const float*)d_in[2];
    const float* conv_w    = (const float*)d_in[3];
    const float* conv_b    = (const float*)d_in[4];
    const float* Wq        = (const float*)d_in[5];
    const float* Wv        = (const float*)d_in[6];
    const float* bias      = (const float*)d_in[7];
    const float* w_score   = (const float*)d_in[8];
    const float* b_score   = (const float*)d_in[9];

    char* ws = (char*)d_ws;
    _Float16* Bpack = (_Float16*)ws;           // 524288 B
    float* qb     = (float*)(ws + 524288);     // 32768 B
    float* sbuf   = (float*)(ws + 557056);     // 262144 B
    float* ssum   = (float*)(ws + 819200);     // 64 B
    float* ctx    = (float*)(ws + 819264);     // 32768 B
    float* out    = (float*)d_out;

    prep_kernel<<<97, 256, 0, stream>>>(query, conv_b, Wq, Wv, bias, Bpack, qb, ssum, ctx);
    gemm_fused_kernel<<<1024, 512, 0, stream>>>(value, last_attn, conv_w, w_score,
                                                b_score, Bpack, qb, sbuf, ssum, ctx);
    finalize_kernel<<<320, 256, 0, stream>>>(query, ctx, sbuf, ssum, out);
}